// Round 10
// baseline (270.374 us; speedup 1.0000x reference)
//
#include <hip/hip_runtime.h>
#include <math.h>

// GCN 3-layer forward, round 10 (round-9 fix: gemm_body arg count).
//  F_init   : zero cnt + detect idx dtype + pack W_in/W1 (bf16 B-frags) + x->bf16
//  F_g1fp   : gemm1 (Xb @ wpk1 -> B0)  ||  fill_pos   (horizontal fusion)
//  scanA/B/C: rowstart + dinv
//  fill_place: srcs (ushort) counting-sort placement
//  agg_node : layer-1 aggregation (B0 -> B1, +self +b_in)
//  gemm2    : B1 @ wpk2 -> B0 (MFMA)
//  agg_out  : layer-2 aggregation + relu + @W_out + log_softmax -> d_out
// NOTE: assumes N < 65536 (ushort src ids).

#define THREADS 256

typedef __attribute__((ext_vector_type(8))) short short8v;   // 8 bf16
typedef __attribute__((ext_vector_type(4))) float float4v;   // 4 f32 acc

__device__ __forceinline__ float b2f(unsigned int lo16) {
    return __uint_as_float(lo16 << 16);
}
__device__ __forceinline__ unsigned short f2b(float f) {
    unsigned int u = __float_as_uint(f);
    u += 0x7FFFu + ((u >> 16) & 1u);   // RNE
    return (unsigned short)(u >> 16);
}

// ---- F_init: cnt=0, flag, pack W0/W1 -> B-frag bf16, x -> bf16 -------------
// pack slot s=(ct*4+kb)*64+l : lane l holds B[k=kb*32+(l>>4)*8+e][col=ct*16+(l&15)]
__global__ __launch_bounds__(256) void f_init(const float* __restrict__ x,
                                              const int* __restrict__ idx,
                                              const float* __restrict__ W0,
                                              const float* __restrict__ W1f,
                                              int* __restrict__ flag,
                                              int* __restrict__ cnt,
                                              uint4* __restrict__ wpk0,
                                              uint4* __restrict__ wpk1,
                                              unsigned short* __restrict__ Xb,
                                              int N) {
    int tid = threadIdx.x, bid = blockIdx.x, nb = gridDim.x;
    if (bid == 0 && tid < 64) {
        unsigned long long b = __ballot(idx[2 * tid + 1] == 0);
        if (tid == 0) *flag = (b == 0xFFFFFFFFFFFFFFFFull) ? 1 : 0;
    }
    for (int i = bid * 256 + tid; i < N; i += nb * 256) cnt[i] = 0;
    if (bid < 2) {
        const float* W = bid ? W1f : W0;
        uint4* wpk = bid ? wpk1 : wpk0;
#pragma unroll
        for (int it = 0; it < 8; ++it) {
            int s = it * 256 + tid;
            int ct = s >> 8, kb = (s >> 6) & 3, l = s & 63;
            int col = ct * 16 + (l & 15);
            int k0 = kb * 32 + ((l >> 4) << 3);
            uint4 u;
            u.x = (unsigned int)f2b(W[(k0 + 0) * 128 + col]) | ((unsigned int)f2b(W[(k0 + 1) * 128 + col]) << 16);
            u.y = (unsigned int)f2b(W[(k0 + 2) * 128 + col]) | ((unsigned int)f2b(W[(k0 + 3) * 128 + col]) << 16);
            u.z = (unsigned int)f2b(W[(k0 + 4) * 128 + col]) | ((unsigned int)f2b(W[(k0 + 5) * 128 + col]) << 16);
            u.w = (unsigned int)f2b(W[(k0 + 6) * 128 + col]) | ((unsigned int)f2b(W[(k0 + 7) * 128 + col]) << 16);
            wpk[s] = u;
        }
    }
    int total = N * 32;                      // float4 count
    const float4* x4 = (const float4*)x;
    ushort4* xb4 = (ushort4*)Xb;
    for (int i = bid * 256 + tid; i < total; i += nb * 256) {
        float4 v = x4[i];
        ushort4 o;
        o.x = f2b(v.x); o.y = f2b(v.y); o.z = f2b(v.z); o.w = f2b(v.w);
        xb4[i] = o;
    }
}

// ---- MFMA gemm body (bf16 A): out_bf16[N,128] = A @ W(packed) --------------
__device__ __forceinline__ void gemm_body(const unsigned short* __restrict__ Ab,
                                          const uint4* __restrict__ wpk,
                                          unsigned short* __restrict__ outb,
                                          unsigned short* ol, int base, int N) {
    int tid = threadIdx.x;
    int w = tid >> 6, l = tid & 63;
    int lr = l & 15, lq = l >> 4;
    int arow0 = base + w * 16 + lr;
    int arow1 = base + 64 + w * 16 + lr;
    int ar0 = (arow0 < N) ? arow0 : (N - 1);
    int ar1 = (arow1 < N) ? arow1 : (N - 1);

    float4v acc[2][8];
#pragma unroll
    for (int t = 0; t < 2; ++t)
#pragma unroll
        for (int ct = 0; ct < 8; ++ct) acc[t][ct] = (float4v){0.f, 0.f, 0.f, 0.f};

#pragma unroll
    for (int kb = 0; kb < 4; ++kb) {
        uint4 v0 = *(const uint4*)(Ab + (size_t)ar0 * 128 + kb * 32 + lq * 8);
        uint4 v1 = *(const uint4*)(Ab + (size_t)ar1 * 128 + kb * 32 + lq * 8);
        union { uint4 u; short8v s; } c0, c1; c0.u = v0; c1.u = v1;
        short8v af0 = c0.s, af1 = c1.s;
#pragma unroll
        for (int ct = 0; ct < 8; ++ct) {
            uint4 bv = wpk[(ct * 4 + kb) * 64 + l];
            union { uint4 u; short8v s; } cv; cv.u = bv; short8v bf = cv.s;
            acc[0][ct] = __builtin_amdgcn_mfma_f32_16x16x32_bf16(af0, bf, acc[0][ct], 0, 0, 0);
            acc[1][ct] = __builtin_amdgcn_mfma_f32_16x16x32_bf16(af1, bf, acc[1][ct], 0, 0, 0);
        }
    }
#pragma unroll
    for (int t = 0; t < 2; ++t)
#pragma unroll
        for (int ct = 0; ct < 8; ++ct)
#pragma unroll
            for (int r = 0; r < 4; ++r)
                ol[(t * 64 + w * 16 + lq * 4 + r) * 128 + ct * 16 + lr] = f2b(acc[t][ct][r]);
    __syncthreads();
#pragma unroll
    for (int it = 0; it < 8; ++it) {
        int o = it * 4096 + tid * 16;
        int rr = o >> 8, cb = o & 255;
        int gr = base + rr;
        if (gr < N) {
            uint4 v = *(const uint4*)((const char*)ol + o);
            *(uint4*)((char*)outb + (size_t)gr * 256 + cb) = v;
        }
    }
}

// ---- F_g1fp: blocks < nbg do gemm1; the rest do fill_pos -------------------
__global__ __launch_bounds__(256) void f_g1fp(const unsigned short* __restrict__ Xb,
                                              const uint4* __restrict__ wpk1,
                                              unsigned short* __restrict__ B0,
                                              const int* __restrict__ idx,
                                              const int* __restrict__ flag,
                                              int* __restrict__ cnt,
                                              unsigned int* __restrict__ rec,
                                              int N, int E, int nbg) {
    __shared__ unsigned short ol[128 * 128];   // 32KB (gemm path only)
    if ((int)blockIdx.x < nbg) {
        gemm_body(Xb, wpk1, B0, ol, blockIdx.x * 128, N);
        return;
    }
    int e = (blockIdx.x - nbg) * 256 + threadIdx.x;
    if (e >= E) return;
    int f = *flag;
    int src, dst;
    if (f) { src = idx[2 * e]; dst = idx[2 * (E + e)]; }
    else   { src = idx[e];     dst = idx[E + e]; }
    unsigned int pos = (unsigned int)atomicAdd(&cnt[dst], 1);
    rec[e] = ((unsigned int)src << 16) | (pos & 0xFFFFu);
}

// ---- standalone gemm2 ------------------------------------------------------
__global__ __launch_bounds__(256) void gemm_mfma(const unsigned short* __restrict__ Ab,
                                                 const uint4* __restrict__ wpk,
                                                 unsigned short* __restrict__ outb,
                                                 int N) {
    __shared__ unsigned short ol[128 * 128];
    gemm_body(Ab, wpk, outb, ol, blockIdx.x * 128, N);
}

// ---- parallel scan (3 kernels) --------------------------------------------
__global__ __launch_bounds__(256) void scanA(const int* __restrict__ cnt,
                                             int* __restrict__ bsum, int N) {
    __shared__ int wt[4];
    int tid = threadIdx.x, lane = tid & 63, w = tid >> 6;
    int i = blockIdx.x * 256 + tid;
    int v = (i < N) ? cnt[i] : 0;
    int s = v;
#pragma unroll
    for (int off = 1; off < 64; off <<= 1) {
        int t = __shfl_up(s, off);
        if (lane >= off) s += t;
    }
    if (lane == 63) wt[w] = s;
    __syncthreads();
    if (tid == 0) bsum[blockIdx.x] = wt[0] + wt[1] + wt[2] + wt[3];
}

__global__ __launch_bounds__(256) void scanB(int* __restrict__ bsum,
                                             int* __restrict__ boff,
                                             int* __restrict__ rowstart,
                                             int nb, int N) {
    __shared__ int wt[4];
    __shared__ int wo[5];
    int tid = threadIdx.x, lane = tid & 63, w = tid >> 6;
    int v = (tid < nb) ? bsum[tid] : 0;
    int s = v;
#pragma unroll
    for (int off = 1; off < 64; off <<= 1) {
        int t = __shfl_up(s, off);
        if (lane >= off) s += t;
    }
    if (lane == 63) wt[w] = s;
    __syncthreads();
    if (tid == 0) {
        int run = 0;
#pragma unroll
        for (int k = 0; k < 4; ++k) { wo[k] = run; run += wt[k]; }
        wo[4] = run;
    }
    __syncthreads();
    if (tid < nb) boff[tid] = wo[w] + s - v;
    if (tid == 0) rowstart[N] = wo[4];
}

__global__ __launch_bounds__(256) void scanC(const int* __restrict__ cnt,
                                             const int* __restrict__ boff,
                                             int* __restrict__ rowstart,
                                             float* __restrict__ dinv, int N) {
    __shared__ int wt[4];
    __shared__ int wo[4];
    int tid = threadIdx.x, lane = tid & 63, w = tid >> 6;
    int i = blockIdx.x * 256 + tid;
    int v = (i < N) ? cnt[i] : 0;
    int s = v;
#pragma unroll
    for (int off = 1; off < 64; off <<= 1) {
        int t = __shfl_up(s, off);
        if (lane >= off) s += t;
    }
    if (lane == 63) wt[w] = s;
    __syncthreads();
    if (tid == 0) {
        int run = 0;
#pragma unroll
        for (int k = 0; k < 4; ++k) { wo[k] = run; run += wt[k]; }
    }
    __syncthreads();
    if (i < N) {
        rowstart[i] = boff[blockIdx.x] + wo[w] + (s - v);
        dinv[i] = rsqrtf(1.0f + (float)v);
    }
}

// ---- place src (ushort) at rowstart[dst]+pos, no atomics -------------------
__global__ void fill_place(const int* __restrict__ idx, const int* __restrict__ flag,
                           const unsigned int* __restrict__ rec,
                           const int* __restrict__ rowstart,
                           unsigned short* __restrict__ srcs, int E) {
    int e = blockIdx.x * blockDim.x + threadIdx.x;
    if (e >= E) return;
    int f = *flag;
    int dst = f ? idx[2 * (E + e)] : idx[E + e];
    unsigned int r = rec[e];
    srcs[rowstart[dst] + (int)(r & 0xFFFFu)] = (unsigned short)(r >> 16);
}

// ---- gather-aggregate macro body: 8 edges in flight, 16 lanes/edge ---------
#define AGG_GATHER(hb8, beg, end, dn)                                          \
    for (int j0 = (beg); j0 < (end); j0 += 64) {                               \
        int myj = j0 + lane;                                                   \
        int ms = 0; float md = 0.f;                                            \
        if (myj < (end)) { ms = (int)srcs[myj]; md = dinv[ms]; }               \
        int m = min(64, (end) - j0);                                           \
        for (int k = 0; k < m; k += 8) {                                       \
            int i0 = k + quarter;                                              \
            int i1 = k + 4 + quarter;                                          \
            int s0 = __shfl(ms, i0);                                           \
            int s1 = __shfl(ms, i1);                                           \
            float c0 = (dn) * __shfl(md, i0);                                  \
            float c1 = (dn) * __shfl(md, i1);                                  \
            uint4 v0 = hb8[(size_t)s0 * 16 + q];                               \
            uint4 v1 = hb8[(size_t)s1 * 16 + q];                               \
            a0 += c0 * b2f(v0.x & 0xFFFFu); a1 += c0 * b2f(v0.x >> 16);        \
            a2 += c0 * b2f(v0.y & 0xFFFFu); a3 += c0 * b2f(v0.y >> 16);        \
            a4 += c0 * b2f(v0.z & 0xFFFFu); a5 += c0 * b2f(v0.z >> 16);        \
            a6 += c0 * b2f(v0.w & 0xFFFFu); a7 += c0 * b2f(v0.w >> 16);        \
            a0 += c1 * b2f(v1.x & 0xFFFFu); a1 += c1 * b2f(v1.x >> 16);        \
            a2 += c1 * b2f(v1.y & 0xFFFFu); a3 += c1 * b2f(v1.y >> 16);        \
            a4 += c1 * b2f(v1.z & 0xFFFFu); a5 += c1 * b2f(v1.z >> 16);        \
            a6 += c1 * b2f(v1.w & 0xFFFFu); a7 += c1 * b2f(v1.w >> 16);        \
        }                                                                      \
    }                                                                          \
    a0 += __shfl_xor(a0, 32); a1 += __shfl_xor(a1, 32);                        \
    a2 += __shfl_xor(a2, 32); a3 += __shfl_xor(a3, 32);                        \
    a4 += __shfl_xor(a4, 32); a5 += __shfl_xor(a5, 32);                        \
    a6 += __shfl_xor(a6, 32); a7 += __shfl_xor(a7, 32);                        \
    a0 += __shfl_xor(a0, 16); a1 += __shfl_xor(a1, 16);                        \
    a2 += __shfl_xor(a2, 16); a3 += __shfl_xor(a3, 16);                        \
    a4 += __shfl_xor(a4, 16); a5 += __shfl_xor(a5, 16);                        \
    a6 += __shfl_xor(a6, 16); a7 += __shfl_xor(a7, 16);

// ---- layer-1 aggregation: one wave/node, +self +bias, write bf16 -----------
__global__ __launch_bounds__(256) void agg_node(const unsigned short* __restrict__ hb,
                                                const int* __restrict__ rowstart,
                                                const unsigned short* __restrict__ srcs,
                                                const float* __restrict__ dinv,
                                                const float* __restrict__ b,
                                                unsigned short* __restrict__ outb,
                                                int N) {
    int w = threadIdx.x >> 6, lane = threadIdx.x & 63;
    int node = blockIdx.x * 4 + w;
    if (node >= N) return;
    int beg = rowstart[node], end = rowstart[node + 1];
    float dn = dinv[node];
    int quarter = lane >> 4, q = lane & 15;
    const uint4* hb8 = (const uint4*)hb;
    float a0 = 0.f, a1 = 0.f, a2 = 0.f, a3 = 0.f;
    float a4 = 0.f, a5 = 0.f, a6 = 0.f, a7 = 0.f;
    AGG_GATHER(hb8, beg, end, dn)
    if (quarter == 0) {
        uint4 sv = hb8[(size_t)node * 16 + q];
        float d2 = dn * dn;
        float4 b0 = ((const float4*)b)[2 * q];
        float4 b1 = ((const float4*)b)[2 * q + 1];
        float r0 = a0 + d2 * b2f(sv.x & 0xFFFFu) + b0.x;
        float r1 = a1 + d2 * b2f(sv.x >> 16)     + b0.y;
        float r2 = a2 + d2 * b2f(sv.y & 0xFFFFu) + b0.z;
        float r3 = a3 + d2 * b2f(sv.y >> 16)     + b0.w;
        float r4 = a4 + d2 * b2f(sv.z & 0xFFFFu) + b1.x;
        float r5 = a5 + d2 * b2f(sv.z >> 16)     + b1.y;
        float r6 = a6 + d2 * b2f(sv.w & 0xFFFFu) + b1.z;
        float r7 = a7 + d2 * b2f(sv.w >> 16)     + b1.w;
        uint4 o;
        o.x = (unsigned int)f2b(r0) | ((unsigned int)f2b(r1) << 16);
        o.y = (unsigned int)f2b(r2) | ((unsigned int)f2b(r3) << 16);
        o.z = (unsigned int)f2b(r4) | ((unsigned int)f2b(r5) << 16);
        o.w = (unsigned int)f2b(r6) | ((unsigned int)f2b(r7) << 16);
        ((uint4*)outb)[(size_t)node * 16 + q] = o;
    }
}

// ---- layer-2 aggregation + relu + output GEMM + log_softmax ---------------
// 256 thr = 4 waves; each wave does 4 nodes sequentially (16 nodes/block).
__global__ __launch_bounds__(256) void agg_out(const unsigned short* __restrict__ hb,
                                               const int* __restrict__ rowstart,
                                               const unsigned short* __restrict__ srcs,
                                               const float* __restrict__ dinv,
                                               const float* __restrict__ b1v,
                                               const float* __restrict__ Wout,
                                               const float* __restrict__ bout,
                                               float* __restrict__ out, int N) {
    __shared__ float Wl[128 * 40];
    __shared__ float bl[40];
    __shared__ float b1l[128];
    __shared__ float rowbuf[4][128];
    int tid = threadIdx.x;
    for (int i = tid; i < 128 * 40; i += 256) Wl[i] = Wout[i];
    if (tid < 40) bl[tid] = bout[tid];
    if (tid < 128) b1l[tid] = b1v[tid];
    __syncthreads();

    int w = tid >> 6, lane = tid & 63;
    int quarter = lane >> 4, q = lane & 15;
    const uint4* hb8 = (const uint4*)hb;

#pragma unroll 1
    for (int nn = 0; nn < 4; ++nn) {
        int node = blockIdx.x * 16 + w * 4 + nn;     // wave-uniform
        bool valid = node < N;
        float a0 = 0.f, a1 = 0.f, a2 = 0.f, a3 = 0.f;
        float a4 = 0.f, a5 = 0.f, a6 = 0.f, a7 = 0.f;
        if (valid) {
            int beg = rowstart[node], end = rowstart[node + 1];
            float dn = dinv[node];
            AGG_GATHER(hb8, beg, end, dn)
            if (quarter == 0) {
                uint4 sv = hb8[(size_t)node * 16 + q];
                float d2 = dn * dn;
                float r0 = fmaxf(a0 + d2 * b2f(sv.x & 0xFFFFu) + b1l[q * 8 + 0], 0.f);
                float r1 = fmaxf(a1 + d2 * b2f(sv.x >> 16)     + b1l[q * 8 + 1], 0.f);
                float r2 = fmaxf(a2 + d2 * b2f(sv.y & 0xFFFFu) + b1l[q * 8 + 2], 0.f);
                float r3 = fmaxf(a3 + d2 * b2f(sv.y >> 16)     + b1l[q * 8 + 3], 0.f);
                float r4 = fmaxf(a4 + d2 * b2f(sv.z & 0xFFFFu) + b1l[q * 8 + 4], 0.f);
                float r5 = fmaxf(a5 + d2 * b2f(sv.z >> 16)     + b1l[q * 8 + 5], 0.f);
                float r6 = fmaxf(a6 + d2 * b2f(sv.w & 0xFFFFu) + b1l[q * 8 + 6], 0.f);
                float r7 = fmaxf(a7 + d2 * b2f(sv.w >> 16)     + b1l[q * 8 + 7], 0.f);
                rowbuf[w][q * 8 + 0] = r0; rowbuf[w][q * 8 + 1] = r1;
                rowbuf[w][q * 8 + 2] = r2; rowbuf[w][q * 8 + 3] = r3;
                rowbuf[w][q * 8 + 4] = r4; rowbuf[w][q * 8 + 5] = r5;
                rowbuf[w][q * 8 + 6] = r6; rowbuf[w][q * 8 + 7] = r7;
            }
        }
        __syncthreads();   // uniform: all waves, all 4 iterations
        float v = -INFINITY;
        if (valid && lane < 40) {
            float acc = 0.f;
#pragma unroll 4
            for (int k = 0; k < 128; ++k) acc += rowbuf[w][k] * Wl[k * 40 + lane];
            v = acc + bl[lane];
        }
        float m = v;
#pragma unroll
        for (int off = 32; off > 0; off >>= 1) m = fmaxf(m, __shfl_xor(m, off));
        float e = (valid && lane < 40) ? expf(v - m) : 0.f;
        float s = e;
#pragma unroll
        for (int off = 32; off > 0; off >>= 1) s += __shfl_xor(s, off);
        float ls = logf(s);
        if (valid && lane < 40) out[(size_t)node * 40 + lane] = v - m - ls;
        __syncthreads();   // protect rowbuf WAR across iterations
    }
}

static inline size_t al256(size_t x) { return (x + 255) & ~(size_t)255; }

extern "C" void kernel_launch(void* const* d_in, const int* in_sizes, int n_in,
                              void* d_out, int out_size, void* d_ws, size_t ws_size,
                              hipStream_t stream) {
    const float* x     = (const float*)d_in[0];
    const int*   idx   = (const int*)d_in[1];
    const float* W_in  = (const float*)d_in[2];
    const float* b_in  = (const float*)d_in[3];
    const float* W1    = (const float*)d_in[4];
    const float* b1    = (const float*)d_in[5];
    const float* W_out = (const float*)d_in[6];
    const float* b_out = (const float*)d_in[7];
    float* out = (float*)d_out;

    int N = in_sizes[0] / 128;
    int E = in_sizes[1] / 2;

    char* ws = (char*)d_ws;
    size_t off = 0;
    int* flag = (int*)(ws + off);              off += 256;
    int* cnt = (int*)(ws + off);               off += al256((size_t)N * 4);
    int* rowstart = (int*)(ws + off);          off += al256((size_t)(N + 1) * 4);
    float* dinv = (float*)(ws + off);          off += al256((size_t)N * 4);
    unsigned short* srcs = (unsigned short*)(ws + off); off += al256((size_t)E * 2);
    unsigned int* rec = (unsigned int*)(ws + off);      off += al256((size_t)E * 4);
    int* bsum = (int*)(ws + off);              off += 2048;
    int* boff = (int*)(ws + off);              off += 2048;
    uint4* wpk1 = (uint4*)(ws + off);          off += 32768;
    uint4* wpk2 = (uint4*)(ws + off);          off += 32768;
    unsigned short* Xb = (unsigned short*)(ws + off);   off += (size_t)N * 128 * 2;
    unsigned short* B0 = (unsigned short*)(ws + off);   off += (size_t)N * 128 * 2;
    unsigned short* B1 = (unsigned short*)(ws + off);

    int nb_e = (E + THREADS - 1) / THREADS;
    int nb_n = (N + THREADS - 1) / THREADS;   // <=256 for N<=65536
    int nb_g = (N + 127) / 128;
    int nb_a = (N + 3) / 4;
    int nb_o = (N + 15) / 16;

    f_init<<<256, THREADS, 0, stream>>>(x, idx, W_in, W1, flag, cnt, wpk1, wpk2, Xb, N);
    f_g1fp<<<nb_g + nb_e, THREADS, 0, stream>>>(Xb, wpk1, B0, idx, flag, cnt, rec,
                                                N, E, nb_g);
    scanA<<<nb_n, THREADS, 0, stream>>>(cnt, bsum, N);
    scanB<<<1, THREADS, 0, stream>>>(bsum, boff, rowstart, nb_n, N);
    scanC<<<nb_n, THREADS, 0, stream>>>(cnt, boff, rowstart, dinv, N);
    fill_place<<<nb_e, THREADS, 0, stream>>>(idx, flag, rec, rowstart, srcs, E);

    agg_node<<<nb_a, THREADS, 0, stream>>>(B0, rowstart, srcs, dinv, b_in, B1, N);
    gemm_mfma<<<nb_g, THREADS, 0, stream>>>(B1, wpk2, B0, N);
    agg_out<<<nb_o, THREADS, 0, stream>>>(B0, rowstart, srcs, dinv, b1,
                                          W_out, b_out, out, N);
}

// Round 11
// 256.029 us; speedup vs baseline: 1.0560x; 1.0560x over previous
//
#include <hip/hip_runtime.h>
#include <math.h>

// GCN 3-layer forward, round 11: keep f_init/f_g1fp fusions, UNFUSE agg_out
// (round-10 barrier-coupled fusion regressed: 83us vs 46us separate).
//  F_init   : zero cnt + detect idx dtype + pack W_in/W1 + x->bf16
//  F_g1fp   : gemm1 (Xb @ wpk1 -> B0)  ||  fill_pos
//  scanA/B/C: rowstart + dinv
//  fill_place: srcs (ushort) placement
//  agg_node : layer-1 agg (B0 -> B1, +self +b_in)
//  gemm2    : B1 @ wpk2 -> B0 (MFMA)
//  agg_node : layer-2 agg (B0 -> B1, +self +b1, relu)
//  out_gemm : log_softmax(B1 @ W_out + b_out) -> d_out
// NOTE: assumes N < 65536 (ushort src ids).

#define THREADS 256

typedef __attribute__((ext_vector_type(8))) short short8v;   // 8 bf16
typedef __attribute__((ext_vector_type(4))) float float4v;   // 4 f32 acc

__device__ __forceinline__ float b2f(unsigned int lo16) {
    return __uint_as_float(lo16 << 16);
}
__device__ __forceinline__ unsigned short f2b(float f) {
    unsigned int u = __float_as_uint(f);
    u += 0x7FFFu + ((u >> 16) & 1u);   // RNE
    return (unsigned short)(u >> 16);
}

// ---- F_init: cnt=0, flag, pack W0/W1 -> B-frag bf16, x -> bf16 -------------
__global__ __launch_bounds__(256) void f_init(const float* __restrict__ x,
                                              const int* __restrict__ idx,
                                              const float* __restrict__ W0,
                                              const float* __restrict__ W1f,
                                              int* __restrict__ flag,
                                              int* __restrict__ cnt,
                                              uint4* __restrict__ wpk0,
                                              uint4* __restrict__ wpk1,
                                              unsigned short* __restrict__ Xb,
                                              int N) {
    int tid = threadIdx.x, bid = blockIdx.x, nb = gridDim.x;
    if (bid == 0 && tid < 64) {
        unsigned long long b = __ballot(idx[2 * tid + 1] == 0);
        if (tid == 0) *flag = (b == 0xFFFFFFFFFFFFFFFFull) ? 1 : 0;
    }
    for (int i = bid * 256 + tid; i < N; i += nb * 256) cnt[i] = 0;
    if (bid < 2) {
        const float* W = bid ? W1f : W0;
        uint4* wpk = bid ? wpk1 : wpk0;
#pragma unroll
        for (int it = 0; it < 8; ++it) {
            int s = it * 256 + tid;
            int ct = s >> 8, kb = (s >> 6) & 3, l = s & 63;
            int col = ct * 16 + (l & 15);
            int k0 = kb * 32 + ((l >> 4) << 3);
            uint4 u;
            u.x = (unsigned int)f2b(W[(k0 + 0) * 128 + col]) | ((unsigned int)f2b(W[(k0 + 1) * 128 + col]) << 16);
            u.y = (unsigned int)f2b(W[(k0 + 2) * 128 + col]) | ((unsigned int)f2b(W[(k0 + 3) * 128 + col]) << 16);
            u.z = (unsigned int)f2b(W[(k0 + 4) * 128 + col]) | ((unsigned int)f2b(W[(k0 + 5) * 128 + col]) << 16);
            u.w = (unsigned int)f2b(W[(k0 + 6) * 128 + col]) | ((unsigned int)f2b(W[(k0 + 7) * 128 + col]) << 16);
            wpk[s] = u;
        }
    }
    int total = N * 32;                      // float4 count
    const float4* x4 = (const float4*)x;
    ushort4* xb4 = (ushort4*)Xb;
    for (int i = bid * 256 + tid; i < total; i += nb * 256) {
        float4 v = x4[i];
        ushort4 o;
        o.x = f2b(v.x); o.y = f2b(v.y); o.z = f2b(v.z); o.w = f2b(v.w);
        xb4[i] = o;
    }
}

// ---- MFMA gemm body (bf16 A): out_bf16[N,128] = A @ W(packed) --------------
__device__ __forceinline__ void gemm_body(const unsigned short* __restrict__ Ab,
                                          const uint4* __restrict__ wpk,
                                          unsigned short* __restrict__ outb,
                                          unsigned short* ol, int base, int N) {
    int tid = threadIdx.x;
    int w = tid >> 6, l = tid & 63;
    int lr = l & 15, lq = l >> 4;
    int arow0 = base + w * 16 + lr;
    int arow1 = base + 64 + w * 16 + lr;
    int ar0 = (arow0 < N) ? arow0 : (N - 1);
    int ar1 = (arow1 < N) ? arow1 : (N - 1);

    float4v acc[2][8];
#pragma unroll
    for (int t = 0; t < 2; ++t)
#pragma unroll
        for (int ct = 0; ct < 8; ++ct) acc[t][ct] = (float4v){0.f, 0.f, 0.f, 0.f};

#pragma unroll
    for (int kb = 0; kb < 4; ++kb) {
        uint4 v0 = *(const uint4*)(Ab + (size_t)ar0 * 128 + kb * 32 + lq * 8);
        uint4 v1 = *(const uint4*)(Ab + (size_t)ar1 * 128 + kb * 32 + lq * 8);
        union { uint4 u; short8v s; } c0, c1; c0.u = v0; c1.u = v1;
        short8v af0 = c0.s, af1 = c1.s;
#pragma unroll
        for (int ct = 0; ct < 8; ++ct) {
            uint4 bv = wpk[(ct * 4 + kb) * 64 + l];
            union { uint4 u; short8v s; } cv; cv.u = bv; short8v bf = cv.s;
            acc[0][ct] = __builtin_amdgcn_mfma_f32_16x16x32_bf16(af0, bf, acc[0][ct], 0, 0, 0);
            acc[1][ct] = __builtin_amdgcn_mfma_f32_16x16x32_bf16(af1, bf, acc[1][ct], 0, 0, 0);
        }
    }
#pragma unroll
    for (int t = 0; t < 2; ++t)
#pragma unroll
        for (int ct = 0; ct < 8; ++ct)
#pragma unroll
            for (int r = 0; r < 4; ++r)
                ol[(t * 64 + w * 16 + lq * 4 + r) * 128 + ct * 16 + lr] = f2b(acc[t][ct][r]);
    __syncthreads();
#pragma unroll
    for (int it = 0; it < 8; ++it) {
        int o = it * 4096 + tid * 16;
        int rr = o >> 8, cb = o & 255;
        int gr = base + rr;
        if (gr < N) {
            uint4 v = *(const uint4*)((const char*)ol + o);
            *(uint4*)((char*)outb + (size_t)gr * 256 + cb) = v;
        }
    }
}

// ---- F_g1fp: blocks < nbg do gemm1; the rest do fill_pos -------------------
__global__ __launch_bounds__(256) void f_g1fp(const unsigned short* __restrict__ Xb,
                                              const uint4* __restrict__ wpk1,
                                              unsigned short* __restrict__ B0,
                                              const int* __restrict__ idx,
                                              const int* __restrict__ flag,
                                              int* __restrict__ cnt,
                                              unsigned int* __restrict__ rec,
                                              int N, int E, int nbg) {
    __shared__ unsigned short ol[128 * 128];   // 32KB (gemm path only)
    if ((int)blockIdx.x < nbg) {
        gemm_body(Xb, wpk1, B0, ol, blockIdx.x * 128, N);
        return;
    }
    int e = (blockIdx.x - nbg) * 256 + threadIdx.x;
    if (e >= E) return;
    int f = *flag;
    int src, dst;
    if (f) { src = idx[2 * e]; dst = idx[2 * (E + e)]; }
    else   { src = idx[e];     dst = idx[E + e]; }
    unsigned int pos = (unsigned int)atomicAdd(&cnt[dst], 1);
    rec[e] = ((unsigned int)src << 16) | (pos & 0xFFFFu);
}

// ---- standalone gemm2 ------------------------------------------------------
__global__ __launch_bounds__(256) void gemm_mfma(const unsigned short* __restrict__ Ab,
                                                 const uint4* __restrict__ wpk,
                                                 unsigned short* __restrict__ outb,
                                                 int N) {
    __shared__ unsigned short ol[128 * 128];
    gemm_body(Ab, wpk, outb, ol, blockIdx.x * 128, N);
}

// ---- parallel scan (3 kernels) --------------------------------------------
__global__ __launch_bounds__(256) void scanA(const int* __restrict__ cnt,
                                             int* __restrict__ bsum, int N) {
    __shared__ int wt[4];
    int tid = threadIdx.x, lane = tid & 63, w = tid >> 6;
    int i = blockIdx.x * 256 + tid;
    int v = (i < N) ? cnt[i] : 0;
    int s = v;
#pragma unroll
    for (int off = 1; off < 64; off <<= 1) {
        int t = __shfl_up(s, off);
        if (lane >= off) s += t;
    }
    if (lane == 63) wt[w] = s;
    __syncthreads();
    if (tid == 0) bsum[blockIdx.x] = wt[0] + wt[1] + wt[2] + wt[3];
}

__global__ __launch_bounds__(256) void scanB(int* __restrict__ bsum,
                                             int* __restrict__ boff,
                                             int* __restrict__ rowstart,
                                             int nb, int N) {
    __shared__ int wt[4];
    __shared__ int wo[5];
    int tid = threadIdx.x, lane = tid & 63, w = tid >> 6;
    int v = (tid < nb) ? bsum[tid] : 0;
    int s = v;
#pragma unroll
    for (int off = 1; off < 64; off <<= 1) {
        int t = __shfl_up(s, off);
        if (lane >= off) s += t;
    }
    if (lane == 63) wt[w] = s;
    __syncthreads();
    if (tid == 0) {
        int run = 0;
#pragma unroll
        for (int k = 0; k < 4; ++k) { wo[k] = run; run += wt[k]; }
        wo[4] = run;
    }
    __syncthreads();
    if (tid < nb) boff[tid] = wo[w] + s - v;
    if (tid == 0) rowstart[N] = wo[4];
}

__global__ __launch_bounds__(256) void scanC(const int* __restrict__ cnt,
                                             const int* __restrict__ boff,
                                             int* __restrict__ rowstart,
                                             float* __restrict__ dinv, int N) {
    __shared__ int wt[4];
    __shared__ int wo[4];
    int tid = threadIdx.x, lane = tid & 63, w = tid >> 6;
    int i = blockIdx.x * 256 + tid;
    int v = (i < N) ? cnt[i] : 0;
    int s = v;
#pragma unroll
    for (int off = 1; off < 64; off <<= 1) {
        int t = __shfl_up(s, off);
        if (lane >= off) s += t;
    }
    if (lane == 63) wt[w] = s;
    __syncthreads();
    if (tid == 0) {
        int run = 0;
#pragma unroll
        for (int k = 0; k < 4; ++k) { wo[k] = run; run += wt[k]; }
    }
    __syncthreads();
    if (i < N) {
        rowstart[i] = boff[blockIdx.x] + wo[w] + (s - v);
        dinv[i] = rsqrtf(1.0f + (float)v);
    }
}

// ---- place src (ushort) at rowstart[dst]+pos, no atomics -------------------
__global__ void fill_place(const int* __restrict__ idx, const int* __restrict__ flag,
                           const unsigned int* __restrict__ rec,
                           const int* __restrict__ rowstart,
                           unsigned short* __restrict__ srcs, int E) {
    int e = blockIdx.x * blockDim.x + threadIdx.x;
    if (e >= E) return;
    int f = *flag;
    int dst = f ? idx[2 * (E + e)] : idx[E + e];
    unsigned int r = rec[e];
    srcs[rowstart[dst] + (int)(r & 0xFFFFu)] = (unsigned short)(r >> 16);
}

// ---- layer aggregation: one wave/node, 8 edges in flight, 16 lanes/edge ----
__global__ __launch_bounds__(256) void agg_node(const unsigned short* __restrict__ hb,
                                                const int* __restrict__ rowstart,
                                                const unsigned short* __restrict__ srcs,
                                                const float* __restrict__ dinv,
                                                const float* __restrict__ b,
                                                unsigned short* __restrict__ outb,
                                                int N, int do_relu) {
    int w = threadIdx.x >> 6, lane = threadIdx.x & 63;
    int node = blockIdx.x * 4 + w;
    if (node >= N) return;
    int beg = rowstart[node], end = rowstart[node + 1];
    float dn = dinv[node];
    int quarter = lane >> 4, q = lane & 15;
    const uint4* hb8 = (const uint4*)hb;
    float a0 = 0.f, a1 = 0.f, a2 = 0.f, a3 = 0.f;
    float a4 = 0.f, a5 = 0.f, a6 = 0.f, a7 = 0.f;

    for (int j0 = beg; j0 < end; j0 += 64) {
        int myj = j0 + lane;
        int ms = 0; float md = 0.f;
        if (myj < end) { ms = (int)srcs[myj]; md = dinv[ms]; }
        int m = min(64, end - j0);
        for (int k = 0; k < m; k += 8) {
            int i0 = k + quarter;
            int i1 = k + 4 + quarter;        // may exceed m on tails: c1=0 there
            int s0 = __shfl(ms, i0);
            int s1 = __shfl(ms, i1);
            float c0 = dn * __shfl(md, i0);
            float c1 = dn * __shfl(md, i1);
            uint4 v0 = hb8[(size_t)s0 * 16 + q];
            uint4 v1 = hb8[(size_t)s1 * 16 + q];
            a0 += c0 * b2f(v0.x & 0xFFFFu); a1 += c0 * b2f(v0.x >> 16);
            a2 += c0 * b2f(v0.y & 0xFFFFu); a3 += c0 * b2f(v0.y >> 16);
            a4 += c0 * b2f(v0.z & 0xFFFFu); a5 += c0 * b2f(v0.z >> 16);
            a6 += c0 * b2f(v0.w & 0xFFFFu); a7 += c0 * b2f(v0.w >> 16);
            a0 += c1 * b2f(v1.x & 0xFFFFu); a1 += c1 * b2f(v1.x >> 16);
            a2 += c1 * b2f(v1.y & 0xFFFFu); a3 += c1 * b2f(v1.y >> 16);
            a4 += c1 * b2f(v1.z & 0xFFFFu); a5 += c1 * b2f(v1.z >> 16);
            a6 += c1 * b2f(v1.w & 0xFFFFu); a7 += c1 * b2f(v1.w >> 16);
        }
    }
    a0 += __shfl_xor(a0, 32); a1 += __shfl_xor(a1, 32);
    a2 += __shfl_xor(a2, 32); a3 += __shfl_xor(a3, 32);
    a4 += __shfl_xor(a4, 32); a5 += __shfl_xor(a5, 32);
    a6 += __shfl_xor(a6, 32); a7 += __shfl_xor(a7, 32);
    a0 += __shfl_xor(a0, 16); a1 += __shfl_xor(a1, 16);
    a2 += __shfl_xor(a2, 16); a3 += __shfl_xor(a3, 16);
    a4 += __shfl_xor(a4, 16); a5 += __shfl_xor(a5, 16);
    a6 += __shfl_xor(a6, 16); a7 += __shfl_xor(a7, 16);

    if (quarter == 0) {
        uint4 sv = hb8[(size_t)node * 16 + q];
        float d2 = dn * dn;
        float4 b0 = ((const float4*)b)[2 * q];
        float4 b1 = ((const float4*)b)[2 * q + 1];
        float r0 = a0 + d2 * b2f(sv.x & 0xFFFFu) + b0.x;
        float r1 = a1 + d2 * b2f(sv.x >> 16)     + b0.y;
        float r2 = a2 + d2 * b2f(sv.y & 0xFFFFu) + b0.z;
        float r3 = a3 + d2 * b2f(sv.y >> 16)     + b0.w;
        float r4 = a4 + d2 * b2f(sv.z & 0xFFFFu) + b1.x;
        float r5 = a5 + d2 * b2f(sv.z >> 16)     + b1.y;
        float r6 = a6 + d2 * b2f(sv.w & 0xFFFFu) + b1.z;
        float r7 = a7 + d2 * b2f(sv.w >> 16)     + b1.w;
        if (do_relu) {
            r0 = fmaxf(r0, 0.f); r1 = fmaxf(r1, 0.f);
            r2 = fmaxf(r2, 0.f); r3 = fmaxf(r3, 0.f);
            r4 = fmaxf(r4, 0.f); r5 = fmaxf(r5, 0.f);
            r6 = fmaxf(r6, 0.f); r7 = fmaxf(r7, 0.f);
        }
        uint4 o;
        o.x = (unsigned int)f2b(r0) | ((unsigned int)f2b(r1) << 16);
        o.y = (unsigned int)f2b(r2) | ((unsigned int)f2b(r3) << 16);
        o.z = (unsigned int)f2b(r4) | ((unsigned int)f2b(r5) << 16);
        o.w = (unsigned int)f2b(r6) | ((unsigned int)f2b(r7) << 16);
        ((uint4*)outb)[(size_t)node * 16 + q] = o;
    }
}

// ---- output: out[N,40] = log_softmax(h2 @ W_out + b_out) -------------------
// 128 rows x 40 cols per block; thread (r4,cg): 4 rows x 5 cols microtile.
__global__ __launch_bounds__(256) void out_gemm(const unsigned short* __restrict__ h2b,
                                                const float* __restrict__ Wout,
                                                const float* __restrict__ bout,
                                                float* __restrict__ out, int N) {
    __shared__ float Xt[128 * 128];  // Xt[k][r], f32
    __shared__ float Wl[128 * 40];
    __shared__ float bl[40];
    int tid = threadIdx.x;
    int row0 = blockIdx.x * 128;

    for (int i = tid; i < 128 * 40; i += 256) Wl[i] = Wout[i];
    if (tid < 40) bl[tid] = bout[tid];

    {
        int r = tid >> 1, kh = tid & 1;
        int gr = row0 + r;
#pragma unroll
        for (int i = 0; i < 16; ++i) {
            int k = kh * 64 + i * 4;
            float f0, f1, f2, f3;
            if (gr < N) {
                uint2 qv = ((const uint2*)h2b)[(size_t)gr * 32 + (k >> 2)];
                f0 = b2f(qv.x & 0xFFFFu); f1 = b2f(qv.x >> 16);
                f2 = b2f(qv.y & 0xFFFFu); f3 = b2f(qv.y >> 16);
            } else {
                f0 = f1 = f2 = f3 = 0.f;
            }
            Xt[(k + 0) * 128 + r] = f0;
            Xt[(k + 1) * 128 + r] = f1;
            Xt[(k + 2) * 128 + r] = f2;
            Xt[(k + 3) * 128 + r] = f3;
        }
    }
    __syncthreads();

    int cg = tid & 7;    // cols 5cg..5cg+4
    int r4 = tid >> 3;   // rows r4*4..r4*4+3
    float bias[5];
#pragma unroll
    for (int c = 0; c < 5; ++c) bias[c] = bl[5 * cg + c];

    float acc[4][5];
#pragma unroll
    for (int j = 0; j < 4; ++j)
#pragma unroll
        for (int c = 0; c < 5; ++c) acc[j][c] = 0.f;

    const float4* Xt4 = (const float4*)Xt;
#pragma unroll 4
    for (int k = 0; k < 128; ++k) {
        float4 xv = Xt4[k * 32 + r4];
        const float* wr = &Wl[k * 40 + 5 * cg];
        float w0 = wr[0], w1 = wr[1], w2 = wr[2], w3 = wr[3], w4 = wr[4];
        float xs[4] = {xv.x, xv.y, xv.z, xv.w};
#pragma unroll
        for (int j = 0; j < 4; ++j) {
            acc[j][0] += xs[j] * w0;
            acc[j][1] += xs[j] * w1;
            acc[j][2] += xs[j] * w2;
            acc[j][3] += xs[j] * w3;
            acc[j][4] += xs[j] * w4;
        }
    }

#pragma unroll
    for (int j = 0; j < 4; ++j) {
        int r = row0 + r4 * 4 + j;
        if (r >= N) continue;   // uniform across the 8-lane shfl group
        float v[5];
        float m = -INFINITY;
#pragma unroll
        for (int c = 0; c < 5; ++c) { v[c] = acc[j][c] + bias[c]; m = fmaxf(m, v[c]); }
        m = fmaxf(m, __shfl_xor(m, 1));
        m = fmaxf(m, __shfl_xor(m, 2));
        m = fmaxf(m, __shfl_xor(m, 4));
        float s = 0.f;
#pragma unroll
        for (int c = 0; c < 5; ++c) s += expf(v[c] - m);
        s += __shfl_xor(s, 1);
        s += __shfl_xor(s, 2);
        s += __shfl_xor(s, 4);
        float ls = logf(s);
#pragma unroll
        for (int c = 0; c < 5; ++c) out[(size_t)r * 40 + 5 * cg + c] = v[c] - m - ls;
    }
}

static inline size_t al256(size_t x) { return (x + 255) & ~(size_t)255; }

extern "C" void kernel_launch(void* const* d_in, const int* in_sizes, int n_in,
                              void* d_out, int out_size, void* d_ws, size_t ws_size,
                              hipStream_t stream) {
    const float* x     = (const float*)d_in[0];
    const int*   idx   = (const int*)d_in[1];
    const float* W_in  = (const float*)d_in[2];
    const float* b_in  = (const float*)d_in[3];
    const float* W1    = (const float*)d_in[4];
    const float* b1    = (const float*)d_in[5];
    const float* W_out = (const float*)d_in[6];
    const float* b_out = (const float*)d_in[7];
    float* out = (float*)d_out;

    int N = in_sizes[0] / 128;
    int E = in_sizes[1] / 2;

    char* ws = (char*)d_ws;
    size_t off = 0;
    int* flag = (int*)(ws + off);              off += 256;
    int* cnt = (int*)(ws + off);               off += al256((size_t)N * 4);
    int* rowstart = (int*)(ws + off);          off += al256((size_t)(N + 1) * 4);
    float* dinv = (float*)(ws + off);          off += al256((size_t)N * 4);
    unsigned short* srcs = (unsigned short*)(ws + off); off += al256((size_t)E * 2);
    unsigned int* rec = (unsigned int*)(ws + off);      off += al256((size_t)E * 4);
    int* bsum = (int*)(ws + off);              off += 2048;
    int* boff = (int*)(ws + off);              off += 2048;
    uint4* wpk1 = (uint4*)(ws + off);          off += 32768;
    uint4* wpk2 = (uint4*)(ws + off);          off += 32768;
    unsigned short* Xb = (unsigned short*)(ws + off);   off += (size_t)N * 128 * 2;
    unsigned short* B0 = (unsigned short*)(ws + off);   off += (size_t)N * 128 * 2;
    unsigned short* B1 = (unsigned short*)(ws + off);

    int nb_e = (E + THREADS - 1) / THREADS;
    int nb_n = (N + THREADS - 1) / THREADS;   // <=256 for N<=65536
    int nb_g = (N + 127) / 128;
    int nb_a = (N + 3) / 4;

    f_init<<<256, THREADS, 0, stream>>>(x, idx, W_in, W1, flag, cnt, wpk1, wpk2, Xb, N);
    f_g1fp<<<nb_g + nb_e, THREADS, 0, stream>>>(Xb, wpk1, B0, idx, flag, cnt, rec,
                                                N, E, nb_g);
    scanA<<<nb_n, THREADS, 0, stream>>>(cnt, bsum, N);
    scanB<<<1, THREADS, 0, stream>>>(bsum, boff, rowstart, nb_n, N);
    scanC<<<nb_n, THREADS, 0, stream>>>(cnt, boff, rowstart, dinv, N);
    fill_place<<<nb_e, THREADS, 0, stream>>>(idx, flag, rec, rowstart, srcs, E);

    agg_node<<<nb_a, THREADS, 0, stream>>>(B0, rowstart, srcs, dinv, b_in, B1, N, 0);
    gemm_mfma<<<nb_g, THREADS, 0, stream>>>(B1, wpk2, B0, N);
    agg_node<<<nb_a, THREADS, 0, stream>>>(B0, rowstart, srcs, dinv, b1, B1, N, 1);
    out_gemm<<<nb_g, THREADS, 0, stream>>>(B1, W_out, b_out, out, N);
}

// Round 12
// 254.649 us; speedup vs baseline: 1.0618x; 1.0054x over previous
//
#include <hip/hip_runtime.h>
#include <math.h>

// GCN 3-layer forward, round 12:
//  - Barrier-free MFMA GEMM: each wave = independent 16-row tile, private 4KB
//    LDS bounce, NO __syncthreads (r11 gemm was latency-bound on the barrier).
//  - scanB eliminated: scanC self-scans block sums; rowstart[N]=E known.
//  Pipeline: f_init ; f_g1fp(gemm1||fill_pos) ; scanA ; scanC2 ; fill_place ;
//            agg_node ; gemm2 ; agg_node(relu) ; out_gemm.
// NOTE: assumes N < 65536 (ushort src ids).

#define THREADS 256

typedef __attribute__((ext_vector_type(8))) short short8v;   // 8 bf16
typedef __attribute__((ext_vector_type(4))) float float4v;   // 4 f32 acc

__device__ __forceinline__ float b2f(unsigned int lo16) {
    return __uint_as_float(lo16 << 16);
}
__device__ __forceinline__ unsigned short f2b(float f) {
    unsigned int u = __float_as_uint(f);
    u += 0x7FFFu + ((u >> 16) & 1u);   // RNE
    return (unsigned short)(u >> 16);
}

// ---- F_init: cnt=0, flag, pack W0/W1 -> B-frag bf16, x -> bf16 -------------
// pack slot s=(ct*4+kb)*64+l : lane l holds B[k=kb*32+(l>>4)*8+e][col=ct*16+(l&15)]
__global__ __launch_bounds__(256) void f_init(const float* __restrict__ x,
                                              const int* __restrict__ idx,
                                              const float* __restrict__ W0,
                                              const float* __restrict__ W1f,
                                              int* __restrict__ flag,
                                              int* __restrict__ cnt,
                                              uint4* __restrict__ wpk0,
                                              uint4* __restrict__ wpk1,
                                              unsigned short* __restrict__ Xb,
                                              int N) {
    int tid = threadIdx.x, bid = blockIdx.x, nb = gridDim.x;
    if (bid == 0 && tid < 64) {
        unsigned long long b = __ballot(idx[2 * tid + 1] == 0);
        if (tid == 0) *flag = (b == 0xFFFFFFFFFFFFFFFFull) ? 1 : 0;
    }
    for (int i = bid * 256 + tid; i < N; i += nb * 256) cnt[i] = 0;
    if (bid < 2) {
        const float* W = bid ? W1f : W0;
        uint4* wpk = bid ? wpk1 : wpk0;
#pragma unroll
        for (int it = 0; it < 8; ++it) {
            int s = it * 256 + tid;
            int ct = s >> 8, kb = (s >> 6) & 3, l = s & 63;
            int col = ct * 16 + (l & 15);
            int k0 = kb * 32 + ((l >> 4) << 3);
            uint4 u;
            u.x = (unsigned int)f2b(W[(k0 + 0) * 128 + col]) | ((unsigned int)f2b(W[(k0 + 1) * 128 + col]) << 16);
            u.y = (unsigned int)f2b(W[(k0 + 2) * 128 + col]) | ((unsigned int)f2b(W[(k0 + 3) * 128 + col]) << 16);
            u.z = (unsigned int)f2b(W[(k0 + 4) * 128 + col]) | ((unsigned int)f2b(W[(k0 + 5) * 128 + col]) << 16);
            u.w = (unsigned int)f2b(W[(k0 + 6) * 128 + col]) | ((unsigned int)f2b(W[(k0 + 7) * 128 + col]) << 16);
            wpk[s] = u;
        }
    }
    int total = N * 32;                      // float4 count
    const float4* x4 = (const float4*)x;
    ushort4* xb4 = (ushort4*)Xb;
    for (int i = bid * 256 + tid; i < total; i += nb * 256) {
        float4 v = x4[i];
        ushort4 o;
        o.x = f2b(v.x); o.y = f2b(v.y); o.z = f2b(v.z); o.w = f2b(v.w);
        xb4[i] = o;
    }
}

// ---- per-wave MFMA gemm: 16 rows, private LDS bounce, NO barrier -----------
// A-frag lane l: A[row0+(l&15)][kb*32+(l>>4)*8..+7]; B from packed wpk.
__device__ __forceinline__ void gemm_wave(const unsigned short* __restrict__ Ab,
                                          const uint4* __restrict__ wpk,
                                          unsigned short* __restrict__ outb,
                                          unsigned short* olw,  // [16*128] this wave's
                                          int row0, int N) {
    int l = threadIdx.x & 63;
    int lr = l & 15, lq = l >> 4;
    int arow = row0 + lr;
    int ar = (arow < N) ? arow : (N - 1);

    float4v acc[8];
#pragma unroll
    for (int ct = 0; ct < 8; ++ct) acc[ct] = (float4v){0.f, 0.f, 0.f, 0.f};

#pragma unroll
    for (int kb = 0; kb < 4; ++kb) {
        uint4 v = *(const uint4*)(Ab + (size_t)ar * 128 + kb * 32 + lq * 8);
        union { uint4 u; short8v s; } cv; cv.u = v;
        short8v af = cv.s;
#pragma unroll
        for (int ct = 0; ct < 8; ++ct) {
            uint4 bv = wpk[(ct * 4 + kb) * 64 + l];
            union { uint4 u; short8v s; } cb; cb.u = bv;
            acc[ct] = __builtin_amdgcn_mfma_f32_16x16x32_bf16(af, cb.s, acc[ct], 0, 0, 0);
        }
    }
    // D -> private LDS (row-major 16x128 bf16); same-wave, no barrier needed
#pragma unroll
    for (int ct = 0; ct < 8; ++ct)
#pragma unroll
        for (int r = 0; r < 4; ++r)
            olw[(lq * 4 + r) * 128 + ct * 16 + lr] = f2b(acc[ct][r]);
    // coalesced store: 16 rows x 256B = 4KB; 4 x 16B per lane
#pragma unroll
    for (int it = 0; it < 4; ++it) {
        int o = it * 1024 + l * 16;          // byte offset in 4KB
        int rr = o >> 8, cb = o & 255;
        int gr = row0 + rr;
        if (gr < N) {
            uint4 v = *(const uint4*)((const char*)olw + o);
            *(uint4*)((char*)outb + (size_t)gr * 256 + cb) = v;
        }
    }
}

// ---- F_g1fp: blocks < nbg do gemm1 (4 indep wave-tiles); rest do fill_pos --
__global__ __launch_bounds__(256) void f_g1fp(const unsigned short* __restrict__ Xb,
                                              const uint4* __restrict__ wpk1,
                                              unsigned short* __restrict__ B0,
                                              const int* __restrict__ idx,
                                              const int* __restrict__ flag,
                                              int* __restrict__ cnt,
                                              unsigned int* __restrict__ rec,
                                              int N, int E, int nbg) {
    __shared__ unsigned short ol[4][16 * 128];   // 16KB, one slab per wave
    if ((int)blockIdx.x < nbg) {
        int w = threadIdx.x >> 6;
        gemm_wave(Xb, wpk1, B0, ol[w], blockIdx.x * 64 + w * 16, N);
        return;
    }
    int e = (blockIdx.x - nbg) * 256 + threadIdx.x;
    if (e >= E) return;
    int f = *flag;
    int src, dst;
    if (f) { src = idx[2 * e]; dst = idx[2 * (E + e)]; }
    else   { src = idx[e];     dst = idx[E + e]; }
    unsigned int pos = (unsigned int)atomicAdd(&cnt[dst], 1);
    rec[e] = ((unsigned int)src << 16) | (pos & 0xFFFFu);
}

// ---- standalone gemm2: 4 independent wave-tiles per block ------------------
__global__ __launch_bounds__(256) void gemm_mfma(const unsigned short* __restrict__ Ab,
                                                 const uint4* __restrict__ wpk,
                                                 unsigned short* __restrict__ outb,
                                                 int N) {
    __shared__ unsigned short ol[4][16 * 128];
    int w = threadIdx.x >> 6;
    gemm_wave(Ab, wpk, outb, ol[w], blockIdx.x * 64 + w * 16, N);
}

// ---- scanA: per-block sum --------------------------------------------------
__global__ __launch_bounds__(256) void scanA(const int* __restrict__ cnt,
                                             int* __restrict__ bsum, int N) {
    __shared__ int wt[4];
    int tid = threadIdx.x, lane = tid & 63, w = tid >> 6;
    int i = blockIdx.x * 256 + tid;
    int v = (i < N) ? cnt[i] : 0;
    int s = v;
#pragma unroll
    for (int off = 1; off < 64; off <<= 1) {
        int t = __shfl_up(s, off);
        if (lane >= off) s += t;
    }
    if (lane == 63) wt[w] = s;
    __syncthreads();
    if (tid == 0) bsum[blockIdx.x] = wt[0] + wt[1] + wt[2] + wt[3];
}

// ---- scanC2: self-scan of bsum (no scanB), rowstart + dinv -----------------
__global__ __launch_bounds__(256) void scanC2(const int* __restrict__ cnt,
                                              const int* __restrict__ bsum,
                                              int* __restrict__ rowstart,
                                              float* __restrict__ dinv,
                                              int N, int nb, int E) {
    __shared__ int wt[4];
    __shared__ int wo[4];
    __shared__ int blkoff;
    int tid = threadIdx.x, lane = tid & 63, w = tid >> 6;
    if (tid < 64) {
        int acc = 0;
        for (int j = lane; j < (int)blockIdx.x; j += 64) acc += bsum[j];
#pragma unroll
        for (int off = 32; off > 0; off >>= 1) acc += __shfl_xor(acc, off);
        if (lane == 0) blkoff = acc;
    }
    int i = blockIdx.x * 256 + tid;
    int v = (i < N) ? cnt[i] : 0;
    int s = v;
#pragma unroll
    for (int off = 1; off < 64; off <<= 1) {
        int t = __shfl_up(s, off);
        if (lane >= off) s += t;
    }
    if (lane == 63) wt[w] = s;
    __syncthreads();
    if (tid == 0) {
        int run = 0;
#pragma unroll
        for (int k = 0; k < 4; ++k) { wo[k] = run; run += wt[k]; }
    }
    __syncthreads();
    if (i < N) {
        rowstart[i] = blkoff + wo[w] + (s - v);
        dinv[i] = rsqrtf(1.0f + (float)v);
    }
    if (blockIdx.x == 0 && tid == 0) rowstart[N] = E;
}

// ---- place src (ushort) at rowstart[dst]+pos, no atomics -------------------
__global__ void fill_place(const int* __restrict__ idx, const int* __restrict__ flag,
                           const unsigned int* __restrict__ rec,
                           const int* __restrict__ rowstart,
                           unsigned short* __restrict__ srcs, int E) {
    int e = blockIdx.x * blockDim.x + threadIdx.x;
    if (e >= E) return;
    int f = *flag;
    int dst = f ? idx[2 * (E + e)] : idx[E + e];
    unsigned int r = rec[e];
    srcs[rowstart[dst] + (int)(r & 0xFFFFu)] = (unsigned short)(r >> 16);
}

// ---- layer aggregation: one wave/node, 8 edges in flight, 16 lanes/edge ----
__global__ __launch_bounds__(256) void agg_node(const unsigned short* __restrict__ hb,
                                                const int* __restrict__ rowstart,
                                                const unsigned short* __restrict__ srcs,
                                                const float* __restrict__ dinv,
                                                const float* __restrict__ b,
                                                unsigned short* __restrict__ outb,
                                                int N, int do_relu) {
    int w = threadIdx.x >> 6, lane = threadIdx.x & 63;
    int node = blockIdx.x * 4 + w;
    if (node >= N) return;
    int beg = rowstart[node], end = rowstart[node + 1];
    float dn = dinv[node];
    int quarter = lane >> 4, q = lane & 15;
    const uint4* hb8 = (const uint4*)hb;
    float a0 = 0.f, a1 = 0.f, a2 = 0.f, a3 = 0.f;
    float a4 = 0.f, a5 = 0.f, a6 = 0.f, a7 = 0.f;

    for (int j0 = beg; j0 < end; j0 += 64) {
        int myj = j0 + lane;
        int ms = 0; float md = 0.f;
        if (myj < end) { ms = (int)srcs[myj]; md = dinv[ms]; }
        int m = min(64, end - j0);
        for (int k = 0; k < m; k += 8) {
            int i0 = k + quarter;
            int i1 = k + 4 + quarter;        // may exceed m on tails: c1=0 there
            int s0 = __shfl(ms, i0);
            int s1 = __shfl(ms, i1);
            float c0 = dn * __shfl(md, i0);
            float c1 = dn * __shfl(md, i1);
            uint4 v0 = hb8[(size_t)s0 * 16 + q];
            uint4 v1 = hb8[(size_t)s1 * 16 + q];
            a0 += c0 * b2f(v0.x & 0xFFFFu); a1 += c0 * b2f(v0.x >> 16);
            a2 += c0 * b2f(v0.y & 0xFFFFu); a3 += c0 * b2f(v0.y >> 16);
            a4 += c0 * b2f(v0.z & 0xFFFFu); a5 += c0 * b2f(v0.z >> 16);
            a6 += c0 * b2f(v0.w & 0xFFFFu); a7 += c0 * b2f(v0.w >> 16);
            a0 += c1 * b2f(v1.x & 0xFFFFu); a1 += c1 * b2f(v1.x >> 16);
            a2 += c1 * b2f(v1.y & 0xFFFFu); a3 += c1 * b2f(v1.y >> 16);
            a4 += c1 * b2f(v1.z & 0xFFFFu); a5 += c1 * b2f(v1.z >> 16);
            a6 += c1 * b2f(v1.w & 0xFFFFu); a7 += c1 * b2f(v1.w >> 16);
        }
    }
    a0 += __shfl_xor(a0, 32); a1 += __shfl_xor(a1, 32);
    a2 += __shfl_xor(a2, 32); a3 += __shfl_xor(a3, 32);
    a4 += __shfl_xor(a4, 32); a5 += __shfl_xor(a5, 32);
    a6 += __shfl_xor(a6, 32); a7 += __shfl_xor(a7, 32);
    a0 += __shfl_xor(a0, 16); a1 += __shfl_xor(a1, 16);
    a2 += __shfl_xor(a2, 16); a3 += __shfl_xor(a3, 16);
    a4 += __shfl_xor(a4, 16); a5 += __shfl_xor(a5, 16);
    a6 += __shfl_xor(a6, 16); a7 += __shfl_xor(a7, 16);

    if (quarter == 0) {
        uint4 sv = hb8[(size_t)node * 16 + q];
        float d2 = dn * dn;
        float4 b0 = ((const float4*)b)[2 * q];
        float4 b1 = ((const float4*)b)[2 * q + 1];
        float r0 = a0 + d2 * b2f(sv.x & 0xFFFFu) + b0.x;
        float r1 = a1 + d2 * b2f(sv.x >> 16)     + b0.y;
        float r2 = a2 + d2 * b2f(sv.y & 0xFFFFu) + b0.z;
        float r3 = a3 + d2 * b2f(sv.y >> 16)     + b0.w;
        float r4 = a4 + d2 * b2f(sv.z & 0xFFFFu) + b1.x;
        float r5 = a5 + d2 * b2f(sv.z >> 16)     + b1.y;
        float r6 = a6 + d2 * b2f(sv.w & 0xFFFFu) + b1.z;
        float r7 = a7 + d2 * b2f(sv.w >> 16)     + b1.w;
        if (do_relu) {
            r0 = fmaxf(r0, 0.f); r1 = fmaxf(r1, 0.f);
            r2 = fmaxf(r2, 0.f); r3 = fmaxf(r3, 0.f);
            r4 = fmaxf(r4, 0.f); r5 = fmaxf(r5, 0.f);
            r6 = fmaxf(r6, 0.f); r7 = fmaxf(r7, 0.f);
        }
        uint4 o;
        o.x = (unsigned int)f2b(r0) | ((unsigned int)f2b(r1) << 16);
        o.y = (unsigned int)f2b(r2) | ((unsigned int)f2b(r3) << 16);
        o.z = (unsigned int)f2b(r4) | ((unsigned int)f2b(r5) << 16);
        o.w = (unsigned int)f2b(r6) | ((unsigned int)f2b(r7) << 16);
        ((uint4*)outb)[(size_t)node * 16 + q] = o;
    }
}

// ---- output: out[N,40] = log_softmax(h2 @ W_out + b_out) -------------------
__global__ __launch_bounds__(256) void out_gemm(const unsigned short* __restrict__ h2b,
                                                const float* __restrict__ Wout,
                                                const float* __restrict__ bout,
                                                float* __restrict__ out, int N) {
    __shared__ float Xt[128 * 128];  // Xt[k][r], f32
    __shared__ float Wl[128 * 40];
    __shared__ float bl[40];
    int tid = threadIdx.x;
    int row0 = blockIdx.x * 128;

    for (int i = tid; i < 128 * 40; i += 256) Wl[i] = Wout[i];
    if (tid < 40) bl[tid] = bout[tid];

    {
        int r = tid >> 1, kh = tid & 1;
        int gr = row0 + r;
#pragma unroll
        for (int i = 0; i < 16; ++i) {
            int k = kh * 64 + i * 4;
            float f0, f1, f2, f3;
            if (gr < N) {
                uint2 qv = ((const uint2*)h2b)[(size_t)gr * 32 + (k >> 2)];
                f0 = b2f(qv.x & 0xFFFFu); f1 = b2f(qv.x >> 16);
                f2 = b2f(qv.y & 0xFFFFu); f3 = b2f(qv.y >> 16);
            } else {
                f0 = f1 = f2 = f3 = 0.f;
            }
            Xt[(k + 0) * 128 + r] = f0;
            Xt[(k + 1) * 128 + r] = f1;
            Xt[(k + 2) * 128 + r] = f2;
            Xt[(k + 3) * 128 + r] = f3;
        }
    }
    __syncthreads();

    int cg = tid & 7;    // cols 5cg..5cg+4
    int r4 = tid >> 3;   // rows r4*4..r4*4+3
    float bias[5];
#pragma unroll
    for (int c = 0; c < 5; ++c) bias[c] = bl[5 * cg + c];

    float acc[4][5];
#pragma unroll
    for (int j = 0; j < 4; ++j)
#pragma unroll
        for (int c = 0; c < 5; ++c) acc[j][c] = 0.f;

    const float4* Xt4 = (const float4*)Xt;
#pragma unroll 4
    for (int k = 0; k < 128; ++k) {
        float4 xv = Xt4[k * 32 + r4];
        const float* wr = &Wl[k * 40 + 5 * cg];
        float w0 = wr[0], w1 = wr[1], w2 = wr[2], w3 = wr[3], w4 = wr[4];
        float xs[4] = {xv.x, xv.y, xv.z, xv.w};
#pragma unroll
        for (int j = 0; j < 4; ++j) {
            acc[j][0] += xs[j] * w0;
            acc[j][1] += xs[j] * w1;
            acc[j][2] += xs[j] * w2;
            acc[j][3] += xs[j] * w3;
            acc[j][4] += xs[j] * w4;
        }
    }

#pragma unroll
    for (int j = 0; j < 4; ++j) {
        int r = row0 + r4 * 4 + j;
        if (r >= N) continue;   // uniform across the 8-lane shfl group
        float v[5];
        float m = -INFINITY;
#pragma unroll
        for (int c = 0; c < 5; ++c) { v[c] = acc[j][c] + bias[c]; m = fmaxf(m, v[c]); }
        m = fmaxf(m, __shfl_xor(m, 1));
        m = fmaxf(m, __shfl_xor(m, 2));
        m = fmaxf(m, __shfl_xor(m, 4));
        float s = 0.f;
#pragma unroll
        for (int c = 0; c < 5; ++c) s += expf(v[c] - m);
        s += __shfl_xor(s, 1);
        s += __shfl_xor(s, 2);
        s += __shfl_xor(s, 4);
        float ls = logf(s);
#pragma unroll
        for (int c = 0; c < 5; ++c) out[(size_t)r * 40 + 5 * cg + c] = v[c] - m - ls;
    }
}

static inline size_t al256(size_t x) { return (x + 255) & ~(size_t)255; }

extern "C" void kernel_launch(void* const* d_in, const int* in_sizes, int n_in,
                              void* d_out, int out_size, void* d_ws, size_t ws_size,
                              hipStream_t stream) {
    const float* x     = (const float*)d_in[0];
    const int*   idx   = (const int*)d_in[1];
    const float* W_in  = (const float*)d_in[2];
    const float* b_in  = (const float*)d_in[3];
    const float* W1    = (const float*)d_in[4];
    const float* b1    = (const float*)d_in[5];
    const float* W_out = (const float*)d_in[6];
    const float* b_out = (const float*)d_in[7];
    float* out = (float*)d_out;

    int N = in_sizes[0] / 128;
    int E = in_sizes[1] / 2;

    char* ws = (char*)d_ws;
    size_t off = 0;
    int* flag = (int*)(ws + off);              off += 256;
    int* cnt = (int*)(ws + off);               off += al256((size_t)N * 4);
    int* rowstart = (int*)(ws + off);          off += al256((size_t)(N + 1) * 4);
    float* dinv = (float*)(ws + off);          off += al256((size_t)N * 4);
    unsigned short* srcs = (unsigned short*)(ws + off); off += al256((size_t)E * 2);
    unsigned int* rec = (unsigned int*)(ws + off);      off += al256((size_t)E * 4);
    int* bsum = (int*)(ws + off);              off += 2048;
    uint4* wpk1 = (uint4*)(ws + off);          off += 32768;
    uint4* wpk2 = (uint4*)(ws + off);          off += 32768;
    unsigned short* Xb = (unsigned short*)(ws + off);   off += (size_t)N * 128 * 2;
    unsigned short* B0 = (unsigned short*)(ws + off);   off += (size_t)N * 128 * 2;
    unsigned short* B1 = (unsigned short*)(ws + off);

    int nb_e = (E + THREADS - 1) / THREADS;
    int nb_n = (N + THREADS - 1) / THREADS;   // <=256 for N<=65536
    int nb_g = (N + 63) / 64;                 // 64 rows/block (4 indep wave-tiles)
    int nb_a = (N + 3) / 4;
    int nb_o = (N + 127) / 128;

    f_init<<<256, THREADS, 0, stream>>>(x, idx, W_in, W1, flag, cnt, wpk1, wpk2, Xb, N);
    f_g1fp<<<nb_g + nb_e, THREADS, 0, stream>>>(Xb, wpk1, B0, idx, flag, cnt, rec,
                                                N, E, nb_g);
    scanA<<<nb_n, THREADS, 0, stream>>>(cnt, bsum, N);
    scanC2<<<nb_n, THREADS, 0, stream>>>(cnt, bsum, rowstart, dinv, N, nb_n, E);
    fill_place<<<nb_e, THREADS, 0, stream>>>(idx, flag, rec, rowstart, srcs, E);

    agg_node<<<nb_a, THREADS, 0, stream>>>(B0, rowstart, srcs, dinv, b_in, B1, N, 0);
    gemm_mfma<<<nb_g, THREADS, 0, stream>>>(B1, wpk2, B0, N);
    agg_node<<<nb_a, THREADS, 0, stream>>>(B0, rowstart, srcs, dinv, b1, B1, N, 1);
    out_gemm<<<nb_o, THREADS, 0, stream>>>(B1, W_out, b_out, out, N);
}